// Round 1
// baseline (944.232 us; speedup 1.0000x reference)
//
#include <hip/hip_runtime.h>
#include <hip/hip_bf16.h>

typedef __bf16 bf16x8 __attribute__((ext_vector_type(8)));
typedef __bf16 bf16x4 __attribute__((ext_vector_type(4)));
typedef __bf16 bf16x2 __attribute__((ext_vector_type(2)));
typedef float f32x4 __attribute__((ext_vector_type(4)));
using bf16 = __hip_bfloat16;

// ---------------------------------------------------------------------------
// Weight prep: WT[n*K + k] = (bf16) W[k*N + n]   (transpose + f32->bf16)
// ---------------------------------------------------------------------------
__global__ __launch_bounds__(256) void t_k(const float* __restrict__ W,
                                           bf16* __restrict__ WT, int K, int N)
{
    int idx = blockIdx.x * 256 + threadIdx.x;
    if (idx >= K * N) return;
    int n = idx / K, k = idx % K;
    WT[idx] = __float2bfloat16(W[(size_t)k * N + n]);
}

__global__ __launch_bounds__(256) void bcat_k(const float* __restrict__ a, const float* __restrict__ b,
                                              const float* __restrict__ c, const float* __restrict__ d,
                                              float* __restrict__ o)
{
    int i = threadIdx.x + blockIdx.x * 256;
    if (i >= 512) return;
    o[i] = (i < 128) ? a[i] : (i < 256) ? b[i - 128] : (i < 384) ? c[i - 256] : d[i - 384];
}

// ---------------------------------------------------------------------------
// MFMA GEMM: C[M,Nout] = A[M,K] @ WT^T  (WT is [Nout][K] bf16, pre-transposed)
// BM=128, BN=128, BK=128, 512 threads = 8 waves, wave w owns rows w*16..+15.
// LDS: XOR-swizzled 16B chunks (chunk ^ (row&7)), no padding, 64 KB total.
// MODE 0: bf16 out. MODE 2: silu->bf16. MODE 3: +resid -> f32 out.
// rowperm (optional): output row i is written to rowperm[i] (scatter rows).
// ---------------------------------------------------------------------------
template <int MODE, bool AF32>
__global__ __launch_bounds__(512) void gemm2_k(
    const void* __restrict__ Av, const bf16* __restrict__ WT,
    const float* __restrict__ bias, void* __restrict__ Cout,
    const float* __restrict__ resid, const int* __restrict__ rowperm,
    int M, int K, int Nout)
{
    __shared__ __bf16 As[128 * 128];
    __shared__ __bf16 Ws[128 * 128];

    const int tid  = threadIdx.x;
    const int wave = tid >> 6;
    const int lane = tid & 63;
    const int row0 = blockIdx.x * 128;
    const int col0 = blockIdx.y * 128;

    f32x4 acc[8];
#pragma unroll
    for (int i = 0; i < 8; i++) acc[i] = (f32x4){0.f, 0.f, 0.f, 0.f};

    for (int k0 = 0; k0 < K; k0 += 128) {
        // ---- stage A tile (128 x 128) ----
        if constexpr (AF32) {
            const float* A = (const float*)Av;
#pragma unroll
            for (int i = 0; i < 8; i++) {              // 4096 f32x4 chunks (8B bf16 out)
                int idx = tid + i * 512;
                int r = idx >> 5, c4 = idx & 31;
                bf16x4 o;
                if (row0 + r < M) {
                    f32x4 v = *reinterpret_cast<const f32x4*>(A + (size_t)(row0 + r) * K + k0 + c4 * 4);
#pragma unroll
                    for (int j = 0; j < 4; j++) o[j] = (__bf16)v[j];
                } else {
#pragma unroll
                    for (int j = 0; j < 4; j++) o[j] = (__bf16)0.f;
                }
                int col = (c4 >> 1) ^ (r & 7);
                *reinterpret_cast<bf16x4*>(&As[r * 128 + col * 8 + (c4 & 1) * 4]) = o;
            }
        } else {
            const bf16* A = (const bf16*)Av;
#pragma unroll
            for (int i = 0; i < 4; i++) {              // 2048 bf16x8 chunks
                int idx = tid + i * 512;
                int r = idx >> 4, c = idx & 15;
                bf16x8 v;
                if (row0 + r < M) {
                    v = *reinterpret_cast<const bf16x8*>(A + (size_t)(row0 + r) * K + k0 + c * 8);
                } else {
#pragma unroll
                    for (int j = 0; j < 8; j++) v[j] = (__bf16)0.f;
                }
                *reinterpret_cast<bf16x8*>(&As[r * 128 + ((c ^ (r & 7)) * 8)]) = v;
            }
        }
        // ---- stage W tile: WT rows col0..col0+127, k slice ----
#pragma unroll
        for (int i = 0; i < 4; i++) {
            int idx = tid + i * 512;
            int r = idx >> 4, c = idx & 15;
            bf16x8 v = *reinterpret_cast<const bf16x8*>(WT + (size_t)(col0 + r) * K + k0 + c * 8);
            *reinterpret_cast<bf16x8*>(&Ws[r * 128 + ((c ^ (r & 7)) * 8)]) = v;
        }
        __syncthreads();

        const int mrow = wave * 16 + (lane & 15);
        const int kq = lane >> 4;                       // 0..3
#pragma unroll
        for (int kk = 0; kk < 4; kk++) {                // K-steps of 32
            int cidx = kk * 4 + kq;                     // 16B chunk index (pre-swizzle)
            bf16x8 a = *reinterpret_cast<const bf16x8*>(&As[mrow * 128 + ((cidx ^ (mrow & 7)) * 8)]);
#pragma unroll
            for (int ct = 0; ct < 8; ct++) {
                int nrow = ct * 16 + (lane & 15);
                bf16x8 b = *reinterpret_cast<const bf16x8*>(&Ws[nrow * 128 + ((cidx ^ (nrow & 7)) * 8)]);
                acc[ct] = __builtin_amdgcn_mfma_f32_16x16x32_bf16(a, b, acc[ct], 0, 0, 0);
            }
        }
        __syncthreads();
    }

    // epilogue: C/D layout col=lane&15, row=(lane>>4)*4+reg
    const int rbase = row0 + wave * 16 + ((lane >> 4) << 2);
    int orow[4];
#pragma unroll
    for (int r = 0; r < 4; r++) {
        int row = rbase + r;
        orow[r] = (row < M) ? (rowperm ? rowperm[row] : row) : -1;
    }
#pragma unroll
    for (int ct = 0; ct < 8; ct++) {
        int col = col0 + ct * 16 + (lane & 15);
        float bv = bias ? bias[col] : 0.f;
#pragma unroll
        for (int r = 0; r < 4; r++) {
            if (orow[r] < 0) continue;
            float v = acc[ct][r] + bv;
            if constexpr (MODE == 2) v = v / (1.f + __expf(-v));
            if constexpr (MODE == 3) v += resid[(size_t)orow[r] * 128 + col];
            if constexpr (MODE == 3) {
                ((float*)Cout)[(size_t)orow[r] * Nout + col] = v;
            } else {
                ((bf16*)Cout)[(size_t)orow[r] * Nout + col] = __float2bfloat16(v);
            }
        }
    }
}

// ---------------------------------------------------------------------------
// LayerNorm: one wave per row (D=128, 2 channels/lane). f32 in -> bf16 out.
// ---------------------------------------------------------------------------
__global__ __launch_bounds__(256) void ln_k(
    const float* __restrict__ x, const float* __restrict__ g,
    const float* __restrict__ beta, bf16* __restrict__ h, int Nrows)
{
    int row = blockIdx.x * 4 + (threadIdx.x >> 6);
    int lane = threadIdx.x & 63;
    if (row >= Nrows) return;
    size_t base = (size_t)row * 128;
    float v0 = x[base + lane], v1 = x[base + lane + 64];
    float s = v0 + v1, ss = v0 * v0 + v1 * v1;
#pragma unroll
    for (int off = 32; off; off >>= 1) {
        s += __shfl_xor(s, off, 64);
        ss += __shfl_xor(ss, off, 64);
    }
    float mu = s * (1.f / 128.f);
    float var = ss * (1.f / 128.f) - mu * mu;
    float rs = rsqrtf(var + 1e-5f);
    h[base + lane]      = __float2bfloat16((v0 - mu) * rs * g[lane] + beta[lane]);
    h[base + lane + 64] = __float2bfloat16((v1 - mu) * rs * g[lane + 64] + beta[lane + 64]);
}

// ---------------------------------------------------------------------------
// CSR build
// ---------------------------------------------------------------------------
__global__ __launch_bounds__(256) void hist_k(const int* __restrict__ ei, int* __restrict__ cnt, int E)
{
    int e = blockIdx.x * 256 + threadIdx.x;
    if (e < E) atomicAdd(&cnt[ei[E + e]], 1);
}

__global__ __launch_bounds__(1024) void scan_k(const int* __restrict__ cnt, int* __restrict__ offset, int N)
{
    __shared__ int tmp[1024];
    __shared__ int s_running;
    int tid = threadIdx.x;
    if (tid == 0) { s_running = 0; offset[0] = 0; }
    __syncthreads();
    for (int base = 0; base < N; base += 1024) {
        int v = (base + tid < N) ? cnt[base + tid] : 0;
        tmp[tid] = v;
        __syncthreads();
#pragma unroll
        for (int off = 1; off < 1024; off <<= 1) {
            int t = (tid >= off) ? tmp[tid - off] : 0;
            __syncthreads();
            tmp[tid] += t;
            __syncthreads();
        }
        int run = s_running;
        if (base + tid < N) offset[base + tid + 1] = run + tmp[tid];
        __syncthreads();
        if (tid == 0) s_running = run + tmp[1023];
        __syncthreads();
    }
}

// scatter: srcs[j] = src for slot j (dst-sorted); epos[e] = j so the edge
// projection GEMM can write Ep rows directly in dst-sorted order.
__global__ __launch_bounds__(256) void scatter_k(
    const int* __restrict__ ei, const int* __restrict__ offset,
    int* __restrict__ cursor, int* __restrict__ srcs, int* __restrict__ epos, int E)
{
    int e = blockIdx.x * 256 + threadIdx.x;
    if (e >= E) return;
    int src = ei[e];
    int dst = ei[E + e];
    int r = atomicAdd(&cursor[dst], 1);
    int j = offset[dst] + r;
    srcs[j] = src;
    epos[e] = j;
}

// ---------------------------------------------------------------------------
// Fused gather: one wave per dst node; QKVS layout [N][512] = Q|K|V|S (bf16).
// Ep is stored in dst-sorted order -> sequential streaming reads.
// p = exp(q.(k+e)/4); register accumulation; then norm+skip+resid+LN2.
// Lane l holds channels 2l,2l+1; head = l>>3.
// 1-deep software pipeline: edge j+1's K/V/E loads issue while computing j.
// ---------------------------------------------------------------------------
__global__ __launch_bounds__(256) void gather_k(
    const int* __restrict__ srcs, const int* __restrict__ offset,
    const bf16* __restrict__ QKVS, const bf16* __restrict__ Ep,
    const float* __restrict__ x, const float* __restrict__ alpha,
    const float* __restrict__ g, const float* __restrict__ beta,
    float* __restrict__ xn, bf16* __restrict__ h2, int N)
{
    int node = blockIdx.x * 4 + (threadIdx.x >> 6);
    if (node >= N) return;
    int lane = threadIdx.x & 63;
    int c = lane * 2;

    bf16x2 qv = *reinterpret_cast<const bf16x2*>(QKVS + (size_t)node * 512 + c);
    float q0 = (float)qv[0], q1 = (float)qv[1];

    int start = offset[node], end = offset[node + 1];
    float den = 0.f, num0 = 0.f, num1 = 0.f;

    bf16x2 kv, vv, ev;
    if (start < end) {
        const bf16* sp = QKVS + (size_t)srcs[start] * 512 + c;
        kv = *reinterpret_cast<const bf16x2*>(sp + 128);
        vv = *reinterpret_cast<const bf16x2*>(sp + 256);
        ev = *reinterpret_cast<const bf16x2*>(Ep + (size_t)start * 128 + c);
    }
    for (int j = start; j < end; j++) {
        bf16x2 kc = kv, vc = vv, ec = ev;
        if (j + 1 < end) {
            const bf16* sp = QKVS + (size_t)srcs[j + 1] * 512 + c;
            kv = *reinterpret_cast<const bf16x2*>(sp + 128);
            vv = *reinterpret_cast<const bf16x2*>(sp + 256);
            ev = *reinterpret_cast<const bf16x2*>(Ep + (size_t)(j + 1) * 128 + c);
        }
        float e0 = (float)ec[0], e1 = (float)ec[1];
        float part = q0 * ((float)kc[0] + e0) + q1 * ((float)kc[1] + e1);
        part += __shfl_xor(part, 1, 64);
        part += __shfl_xor(part, 2, 64);
        part += __shfl_xor(part, 4, 64);
        float p = __expf(part * 0.25f);
        den  += p;
        num0 += p * ((float)vc[0] + e0);
        num1 += p * ((float)vc[1] + e1);
    }

    size_t base = (size_t)node * 128;
    float invz = 1.f / (den + 1e-16f);
    float al = alpha[0];
    float s0 = (float)QKVS[(size_t)node * 512 + 384 + c];
    float s1 = (float)QKVS[(size_t)node * 512 + 384 + c + 1];
    float o0 = num0 * invz + s0;
    float o1 = num1 * invz + s1;
    float x0 = x[base + c] + al * o0;
    float x1 = x[base + c + 1] + al * o1;
    xn[base + c] = x0;
    xn[base + c + 1] = x1;

    float s = x0 + x1, ss = x0 * x0 + x1 * x1;
#pragma unroll
    for (int off = 32; off; off >>= 1) {
        s += __shfl_xor(s, off, 64);
        ss += __shfl_xor(ss, off, 64);
    }
    float mu = s * (1.f / 128.f);
    float var = ss * (1.f / 128.f) - mu * mu;
    float rs = rsqrtf(var + 1e-5f);
    h2[base + c]     = __float2bfloat16((x0 - mu) * rs * g[c] + beta[c]);
    h2[base + c + 1] = __float2bfloat16((x1 - mu) * rs * g[c + 1] + beta[c + 1]);
}

// ---------------------------------------------------------------------------
extern "C" void kernel_launch(void* const* d_in, const int* in_sizes, int n_in,
                              void* d_out, int out_size, void* d_ws, size_t ws_size,
                              hipStream_t stream)
{
    const float* x         = (const float*)d_in[0];
    const float* edge_attr = (const float*)d_in[1];
    const int*   ei        = (const int*)d_in[2];
    const float* Wq = (const float*)d_in[3];  const float* bq = (const float*)d_in[4];
    const float* Wk = (const float*)d_in[5];  const float* bk = (const float*)d_in[6];
    const float* Wv = (const float*)d_in[7];  const float* bv = (const float*)d_in[8];
    const float* We = (const float*)d_in[9];
    const float* Wskip = (const float*)d_in[10]; const float* bskip = (const float*)d_in[11];
    const float* W1 = (const float*)d_in[12]; const float* b1 = (const float*)d_in[13];
    const float* W2 = (const float*)d_in[14]; const float* b2 = (const float*)d_in[15];
    const float* g1 = (const float*)d_in[16]; const float* beta1 = (const float*)d_in[17];
    const float* g2 = (const float*)d_in[18]; const float* beta2 = (const float*)d_in[19];
    const float* alpha = (const float*)d_in[20];

    const int N = in_sizes[0] / 128;
    const int E = in_sizes[2] / 2;

    char* w = (char*)d_ws;
    auto alloc = [&](size_t bytes) {
        char* p = w;
        w += (bytes + 255) & ~(size_t)255;
        return p;
    };
    bf16*  h      = (bf16*)alloc((size_t)N * 128 * 2);
    bf16*  QKVS   = (bf16*)alloc((size_t)N * 512 * 2);
    bf16*  Ep     = (bf16*)alloc((size_t)E * 128 * 2);
    float* xn     = (float*)alloc((size_t)N * 128 * 4);
    bf16*  h2     = (bf16*)alloc((size_t)N * 128 * 2);
    bf16*  t      = (bf16*)alloc((size_t)N * 512 * 2);
    int*   cnt    = (int*)alloc((size_t)N * 4);
    int*   cursor = (int*)alloc((size_t)N * 4);
    int*   offset = (int*)alloc((size_t)(N + 1) * 4);
    int*   srcs   = (int*)alloc((size_t)E * 4);
    int*   epos   = (int*)alloc((size_t)E * 4);
    bf16*  WTqkvs = (bf16*)alloc((size_t)512 * 128 * 2);
    bf16*  WTe    = (bf16*)alloc((size_t)128 * 128 * 2);
    bf16*  WT1    = (bf16*)alloc((size_t)512 * 128 * 2);
    bf16*  WT2    = (bf16*)alloc((size_t)128 * 512 * 2);
    float* bqkvs  = (float*)alloc((size_t)512 * 4);

    // weight prep (tiny)
    t_k<<<64, 256, 0, stream>>>(Wq, WTqkvs, 128, 128);
    t_k<<<64, 256, 0, stream>>>(Wk, WTqkvs + 128 * 128, 128, 128);
    t_k<<<64, 256, 0, stream>>>(Wv, WTqkvs + 256 * 128, 128, 128);
    t_k<<<64, 256, 0, stream>>>(Wskip, WTqkvs + 384 * 128, 128, 128);
    t_k<<<64, 256, 0, stream>>>(We, WTe, 128, 128);
    t_k<<<256, 256, 0, stream>>>(W1, WT1, 128, 512);
    t_k<<<256, 256, 0, stream>>>(W2, WT2, 512, 128);
    bcat_k<<<2, 256, 0, stream>>>(bq, bk, bv, bskip, bqkvs);

    // CSR build
    hipMemsetAsync(cnt, 0, (size_t)N * 4, stream);
    hipMemsetAsync(cursor, 0, (size_t)N * 4, stream);
    hist_k<<<(E + 255) / 256, 256, 0, stream>>>(ei, cnt, E);
    scan_k<<<1, 1024, 0, stream>>>(cnt, offset, N);
    scatter_k<<<(E + 255) / 256, 256, 0, stream>>>(ei, offset, cursor, srcs, epos, E);

    // LN1
    ln_k<<<(N + 3) / 4, 256, 0, stream>>>(x, g1, beta1, h, N);

    // fused Q|K|V|S GEMM -> QKVS [N][512]
    gemm2_k<0, false><<<dim3((N + 127) / 128, 4), 512, 0, stream>>>(h, WTqkvs, bqkvs, QKVS, nullptr, nullptr, N, 128, 512);

    // edge projection: Ep = edge_attr(f32) @ We -> bf16, rows scattered to dst-sorted order
    gemm2_k<0, true><<<dim3((E + 127) / 128, 1), 512, 0, stream>>>(edge_attr, WTe, nullptr, Ep, nullptr, epos, E, 128, 128);

    // fused gather: attention + normalize + skip + residual + LN2
    gather_k<<<(N + 3) / 4, 256, 0, stream>>>(srcs, offset, QKVS, Ep, x, alpha, g2, beta2, xn, h2, N);

    // FFN
    gemm2_k<2, false><<<dim3((N + 127) / 128, 4), 512, 0, stream>>>(h2, WT1, b1, t, nullptr, nullptr, N, 128, 512);
    gemm2_k<3, false><<<dim3((N + 127) / 128, 1), 512, 0, stream>>>(t, WT2, b2, d_out, xn, nullptr, N, 512, 128);
}

// Round 3
// 903.492 us; speedup vs baseline: 1.0451x; 1.0451x over previous
//
#include <hip/hip_runtime.h>
#include <hip/hip_bf16.h>

typedef __bf16 bf16x8 __attribute__((ext_vector_type(8)));
typedef __bf16 bf16x4 __attribute__((ext_vector_type(4)));
typedef __bf16 bf16x2 __attribute__((ext_vector_type(2)));
typedef float f32x4 __attribute__((ext_vector_type(4)));
using bf16 = __hip_bfloat16;

// ---------------------------------------------------------------------------
// Weight prep: WT[n*K + k] = (bf16) W[k*N + n]   (transpose + f32->bf16)
// ---------------------------------------------------------------------------
__global__ __launch_bounds__(256) void t_k(const float* __restrict__ W,
                                           bf16* __restrict__ WT, int K, int N)
{
    int idx = blockIdx.x * 256 + threadIdx.x;
    if (idx >= K * N) return;
    int n = idx / K, k = idx % K;
    WT[idx] = __float2bfloat16(W[(size_t)k * N + n]);
}

__global__ __launch_bounds__(256) void bcat_k(const float* __restrict__ a, const float* __restrict__ b,
                                              const float* __restrict__ c, const float* __restrict__ d,
                                              float* __restrict__ o)
{
    int i = threadIdx.x + blockIdx.x * 256;
    if (i >= 512) return;
    o[i] = (i < 128) ? a[i] : (i < 256) ? b[i - 128] : (i < 384) ? c[i - 256] : d[i - 384];
}

// ---------------------------------------------------------------------------
// MFMA GEMM: C[M,Nout] = A[M,K] @ WT^T  (WT is [Nout][K] bf16, pre-transposed)
// BM=128, BN=128, BK=128, 512 threads = 8 waves, wave w owns rows w*16..+15.
// LDS: XOR-swizzled 16B chunks (chunk ^ (row&7)), no padding, 64 KB total.
// MODE 0: bf16 out. MODE 2: silu->bf16. MODE 3: +resid -> f32 out.
// rowperm (optional): output row i is written to rowperm[i] (scatter rows).
// ---------------------------------------------------------------------------
template <int MODE, bool AF32>
__global__ __launch_bounds__(512) void gemm2_k(
    const void* __restrict__ Av, const bf16* __restrict__ WT,
    const float* __restrict__ bias, void* __restrict__ Cout,
    const float* __restrict__ resid, const int* __restrict__ rowperm,
    int M, int K, int Nout)
{
    __shared__ __bf16 As[128 * 128];
    __shared__ __bf16 Ws[128 * 128];

    const int tid  = threadIdx.x;
    const int wave = tid >> 6;
    const int lane = tid & 63;
    const int row0 = blockIdx.x * 128;
    const int col0 = blockIdx.y * 128;

    f32x4 acc[8];
#pragma unroll
    for (int i = 0; i < 8; i++) acc[i] = (f32x4){0.f, 0.f, 0.f, 0.f};

    for (int k0 = 0; k0 < K; k0 += 128) {
        // ---- stage A tile (128 x 128) ----
        if constexpr (AF32) {
            const float* A = (const float*)Av;
#pragma unroll
            for (int i = 0; i < 8; i++) {              // 4096 f32x4 chunks (8B bf16 out)
                int idx = tid + i * 512;
                int r = idx >> 5, c4 = idx & 31;
                bf16x4 o;
                if (row0 + r < M) {
                    f32x4 v = *reinterpret_cast<const f32x4*>(A + (size_t)(row0 + r) * K + k0 + c4 * 4);
#pragma unroll
                    for (int j = 0; j < 4; j++) o[j] = (__bf16)v[j];
                } else {
#pragma unroll
                    for (int j = 0; j < 4; j++) o[j] = (__bf16)0.f;
                }
                int col = (c4 >> 1) ^ (r & 7);
                *reinterpret_cast<bf16x4*>(&As[r * 128 + col * 8 + (c4 & 1) * 4]) = o;
            }
        } else {
            const bf16* A = (const bf16*)Av;
#pragma unroll
            for (int i = 0; i < 4; i++) {              // 2048 bf16x8 chunks
                int idx = tid + i * 512;
                int r = idx >> 4, c = idx & 15;
                bf16x8 v;
                if (row0 + r < M) {
                    v = *reinterpret_cast<const bf16x8*>(A + (size_t)(row0 + r) * K + k0 + c * 8);
                } else {
#pragma unroll
                    for (int j = 0; j < 8; j++) v[j] = (__bf16)0.f;
                }
                *reinterpret_cast<bf16x8*>(&As[r * 128 + ((c ^ (r & 7)) * 8)]) = v;
            }
        }
        // ---- stage W tile: WT rows col0..col0+127, k slice ----
#pragma unroll
        for (int i = 0; i < 4; i++) {
            int idx = tid + i * 512;
            int r = idx >> 4, c = idx & 15;
            bf16x8 v = *reinterpret_cast<const bf16x8*>(WT + (size_t)(col0 + r) * K + k0 + c * 8);
            *reinterpret_cast<bf16x8*>(&Ws[r * 128 + ((c ^ (r & 7)) * 8)]) = v;
        }
        __syncthreads();

        const int mrow = wave * 16 + (lane & 15);
        const int kq = lane >> 4;                       // 0..3
#pragma unroll
        for (int kk = 0; kk < 4; kk++) {                // K-steps of 32
            int cidx = kk * 4 + kq;                     // 16B chunk index (pre-swizzle)
            bf16x8 a = *reinterpret_cast<const bf16x8*>(&As[mrow * 128 + ((cidx ^ (mrow & 7)) * 8)]);
#pragma unroll
            for (int ct = 0; ct < 8; ct++) {
                int nrow = ct * 16 + (lane & 15);
                bf16x8 b = *reinterpret_cast<const bf16x8*>(&Ws[nrow * 128 + ((cidx ^ (nrow & 7)) * 8)]);
                acc[ct] = __builtin_amdgcn_mfma_f32_16x16x32_bf16(a, b, acc[ct], 0, 0, 0);
            }
        }
        __syncthreads();
    }

    // epilogue: C/D layout col=lane&15, row=(lane>>4)*4+reg
    const int rbase = row0 + wave * 16 + ((lane >> 4) << 2);
    int orow[4];
#pragma unroll
    for (int r = 0; r < 4; r++) {
        int row = rbase + r;
        orow[r] = (row < M) ? (rowperm ? rowperm[row] : row) : -1;
    }
#pragma unroll
    for (int ct = 0; ct < 8; ct++) {
        int col = col0 + ct * 16 + (lane & 15);
        float bv = bias ? bias[col] : 0.f;
#pragma unroll
        for (int r = 0; r < 4; r++) {
            if (orow[r] < 0) continue;
            float v = acc[ct][r] + bv;
            if constexpr (MODE == 2) v = v / (1.f + __expf(-v));
            if constexpr (MODE == 3) v += resid[(size_t)orow[r] * 128 + col];
            if constexpr (MODE == 3) {
                ((float*)Cout)[(size_t)orow[r] * Nout + col] = v;
            } else {
                ((bf16*)Cout)[(size_t)orow[r] * Nout + col] = __float2bfloat16(v);
            }
        }
    }
}

// ---------------------------------------------------------------------------
// Edge-projection GEMM, specialized: M huge, K=128, N=128, A in f32.
// W (128x128 bf16 = 32 KB) loaded to swizzled LDS ONCE; then a barrier-free
// grid-stride loop, one 16-row tile per wave, A loaded global->reg directly
// in MFMA fragment layout (A has zero reuse at N=128, LDS staging is waste).
// Output rows scattered via rowperm (dst-sorted Ep order).
// ---------------------------------------------------------------------------
__global__ __launch_bounds__(256) void egemm_k(
    const float* __restrict__ A, const bf16* __restrict__ WT,
    bf16* __restrict__ C, const int* __restrict__ rowperm, int M)
{
    __shared__ __bf16 Ws[128 * 128];
#pragma unroll
    for (int i = 0; i < 8; i++) {
        int idx = threadIdx.x + i * 256;
        int r = idx >> 4, c = idx & 15;
        bf16x8 v = *reinterpret_cast<const bf16x8*>(WT + r * 128 + c * 8);
        *reinterpret_cast<bf16x8*>(&Ws[r * 128 + ((c ^ (r & 7)) * 8)]) = v;
    }
    __syncthreads();

    const int lane = threadIdx.x & 63;
    const int wave = threadIdx.x >> 6;
    const int r16  = lane & 15;
    const int kq   = lane >> 4;                         // 0..3
    const int ntiles = (M + 15) >> 4;

    for (int t = blockIdx.x * 4 + wave; t < ntiles; t += gridDim.x * 4) {
        const int row0 = t * 16;
        const int arow = row0 + r16;

        // A fragments: lane holds A[row0 + (lane&15)][kk*32 + (lane>>4)*8 .. +8]
        bf16x8 a[4];
        if (arow < M) {
            const float* ap = A + (size_t)arow * 128 + kq * 8;
#pragma unroll
            for (int kk = 0; kk < 4; kk++) {
                f32x4 lo = *reinterpret_cast<const f32x4*>(ap + kk * 32);
                f32x4 hi = *reinterpret_cast<const f32x4*>(ap + kk * 32 + 4);
#pragma unroll
                for (int j = 0; j < 4; j++) {
                    a[kk][j]     = (__bf16)lo[j];
                    a[kk][j + 4] = (__bf16)hi[j];
                }
            }
        } else {
#pragma unroll
            for (int kk = 0; kk < 4; kk++)
#pragma unroll
                for (int j = 0; j < 8; j++) a[kk][j] = (__bf16)0.f;
        }

        f32x4 acc[8];
#pragma unroll
        for (int i = 0; i < 8; i++) acc[i] = (f32x4){0.f, 0.f, 0.f, 0.f};
#pragma unroll
        for (int kk = 0; kk < 4; kk++) {
            int cidx = kk * 4 + kq;
#pragma unroll
            for (int ct = 0; ct < 8; ct++) {
                int nrow = ct * 16 + r16;
                bf16x8 b = *reinterpret_cast<const bf16x8*>(&Ws[nrow * 128 + ((cidx ^ (nrow & 7)) * 8)]);
                acc[ct] = __builtin_amdgcn_mfma_f32_16x16x32_bf16(a[kk], b, acc[ct], 0, 0, 0);
            }
        }

        // epilogue: C/D layout col=lane&15, row=(lane>>4)*4+reg
        const int rbase = row0 + (kq << 2);
#pragma unroll
        for (int r = 0; r < 4; r++) {
            int row = rbase + r;
            if (row >= M) continue;
            size_t orow = (size_t)(rowperm ? rowperm[row] : row);
#pragma unroll
            for (int ct = 0; ct < 8; ct++) {
                C[orow * 128 + ct * 16 + r16] = __float2bfloat16(acc[ct][r]);
            }
        }
    }
}

// ---------------------------------------------------------------------------
// LayerNorm: one wave per row (D=128, 2 channels/lane). f32 in -> bf16 out.
// ---------------------------------------------------------------------------
__global__ __launch_bounds__(256) void ln_k(
    const float* __restrict__ x, const float* __restrict__ g,
    const float* __restrict__ beta, bf16* __restrict__ h, int Nrows)
{
    int row = blockIdx.x * 4 + (threadIdx.x >> 6);
    int lane = threadIdx.x & 63;
    if (row >= Nrows) return;
    size_t base = (size_t)row * 128;
    float v0 = x[base + lane], v1 = x[base + lane + 64];
    float s = v0 + v1, ss = v0 * v0 + v1 * v1;
#pragma unroll
    for (int off = 32; off; off >>= 1) {
        s += __shfl_xor(s, off, 64);
        ss += __shfl_xor(ss, off, 64);
    }
    float mu = s * (1.f / 128.f);
    float var = ss * (1.f / 128.f) - mu * mu;
    float rs = rsqrtf(var + 1e-5f);
    h[base + lane]      = __float2bfloat16((v0 - mu) * rs * g[lane] + beta[lane]);
    h[base + lane + 64] = __float2bfloat16((v1 - mu) * rs * g[lane + 64] + beta[lane + 64]);
}

// ---------------------------------------------------------------------------
// CSR build
// ---------------------------------------------------------------------------
__global__ __launch_bounds__(256) void hist_k(const int* __restrict__ ei, int* __restrict__ cnt, int E)
{
    int e = blockIdx.x * 256 + threadIdx.x;
    if (e < E) atomicAdd(&cnt[ei[E + e]], 1);
}

__global__ __launch_bounds__(1024) void scan_k(const int* __restrict__ cnt, int* __restrict__ offset, int N)
{
    __shared__ int tmp[1024];
    __shared__ int s_running;
    int tid = threadIdx.x;
    if (tid == 0) { s_running = 0; offset[0] = 0; }
    __syncthreads();
    for (int base = 0; base < N; base += 1024) {
        int v = (base + tid < N) ? cnt[base + tid] : 0;
        tmp[tid] = v;
        __syncthreads();
#pragma unroll
        for (int off = 1; off < 1024; off <<= 1) {
            int t = (tid >= off) ? tmp[tid - off] : 0;
            __syncthreads();
            tmp[tid] += t;
            __syncthreads();
        }
        int run = s_running;
        if (base + tid < N) offset[base + tid + 1] = run + tmp[tid];
        __syncthreads();
        if (tid == 0) s_running = run + tmp[1023];
        __syncthreads();
    }
}

// scatter: srcs[j] = src for slot j (dst-sorted); epos[e] = j so the edge
// projection GEMM can write Ep rows directly in dst-sorted order.
__global__ __launch_bounds__(256) void scatter_k(
    const int* __restrict__ ei, const int* __restrict__ offset,
    int* __restrict__ cursor, int* __restrict__ srcs, int* __restrict__ epos, int E)
{
    int e = blockIdx.x * 256 + threadIdx.x;
    if (e >= E) return;
    int src = ei[e];
    int dst = ei[E + e];
    int r = atomicAdd(&cursor[dst], 1);
    int j = offset[dst] + r;
    srcs[j] = src;
    epos[e] = j;
}

// ---------------------------------------------------------------------------
// Fused gather: one wave per dst node; QKVS layout [N][512] = Q|K|V|S (bf16).
// Ep is stored in dst-sorted order -> sequential streaming reads.
// p = exp(q.(k+e)/4); register accumulation; then norm+skip+resid+LN2.
// Lane l holds channels 2l,2l+1; head = l>>3.
// 1-deep software pipeline: edge j+1's K/V/E loads issue while computing j.
// ---------------------------------------------------------------------------
__global__ __launch_bounds__(256) void gather_k(
    const int* __restrict__ srcs, const int* __restrict__ offset,
    const bf16* __restrict__ QKVS, const bf16* __restrict__ Ep,
    const float* __restrict__ x, const float* __restrict__ alpha,
    const float* __restrict__ g, const float* __restrict__ beta,
    float* __restrict__ xn, bf16* __restrict__ h2, int N)
{
    int node = blockIdx.x * 4 + (threadIdx.x >> 6);
    if (node >= N) return;
    int lane = threadIdx.x & 63;
    int c = lane * 2;

    bf16x2 qv = *reinterpret_cast<const bf16x2*>(QKVS + (size_t)node * 512 + c);
    float q0 = (float)qv[0], q1 = (float)qv[1];

    int start = offset[node], end = offset[node + 1];
    float den = 0.f, num0 = 0.f, num1 = 0.f;

    bf16x2 kv, vv, ev;
    if (start < end) {
        const bf16* sp = QKVS + (size_t)srcs[start] * 512 + c;
        kv = *reinterpret_cast<const bf16x2*>(sp + 128);
        vv = *reinterpret_cast<const bf16x2*>(sp + 256);
        ev = *reinterpret_cast<const bf16x2*>(Ep + (size_t)start * 128 + c);
    }
    for (int j = start; j < end; j++) {
        bf16x2 kc = kv, vc = vv, ec = ev;
        if (j + 1 < end) {
            const bf16* sp = QKVS + (size_t)srcs[j + 1] * 512 + c;
            kv = *reinterpret_cast<const bf16x2*>(sp + 128);
            vv = *reinterpret_cast<const bf16x2*>(sp + 256);
            ev = *reinterpret_cast<const bf16x2*>(Ep + (size_t)(j + 1) * 128 + c);
        }
        float e0 = (float)ec[0], e1 = (float)ec[1];
        float part = q0 * ((float)kc[0] + e0) + q1 * ((float)kc[1] + e1);
        part += __shfl_xor(part, 1, 64);
        part += __shfl_xor(part, 2, 64);
        part += __shfl_xor(part, 4, 64);
        float p = __expf(part * 0.25f);
        den  += p;
        num0 += p * ((float)vc[0] + e0);
        num1 += p * ((float)vc[1] + e1);
    }

    size_t base = (size_t)node * 128;
    float invz = 1.f / (den + 1e-16f);
    float al = alpha[0];
    float s0 = (float)QKVS[(size_t)node * 512 + 384 + c];
    float s1 = (float)QKVS[(size_t)node * 512 + 384 + c + 1];
    float o0 = num0 * invz + s0;
    float o1 = num1 * invz + s1;
    float x0 = x[base + c] + al * o0;
    float x1 = x[base + c + 1] + al * o1;
    xn[base + c] = x0;
    xn[base + c + 1] = x1;

    float s = x0 + x1, ss = x0 * x0 + x1 * x1;
#pragma unroll
    for (int off = 32; off; off >>= 1) {
        s += __shfl_xor(s, off, 64);
        ss += __shfl_xor(ss, off, 64);
    }
    float mu = s * (1.f / 128.f);
    float var = ss * (1.f / 128.f) - mu * mu;
    float rs = rsqrtf(var + 1e-5f);
    h2[base + c]     = __float2bfloat16((x0 - mu) * rs * g[c] + beta[c]);
    h2[base + c + 1] = __float2bfloat16((x1 - mu) * rs * g[c + 1] + beta[c + 1]);
}

// ---------------------------------------------------------------------------
extern "C" void kernel_launch(void* const* d_in, const int* in_sizes, int n_in,
                              void* d_out, int out_size, void* d_ws, size_t ws_size,
                              hipStream_t stream)
{
    const float* x         = (const float*)d_in[0];
    const float* edge_attr = (const float*)d_in[1];
    const int*   ei        = (const int*)d_in[2];
    const float* Wq = (const float*)d_in[3];  const float* bq = (const float*)d_in[4];
    const float* Wk = (const float*)d_in[5];  const float* bk = (const float*)d_in[6];
    const float* Wv = (const float*)d_in[7];  const float* bv = (const float*)d_in[8];
    const float* We = (const float*)d_in[9];
    const float* Wskip = (const float*)d_in[10]; const float* bskip = (const float*)d_in[11];
    const float* W1 = (const float*)d_in[12]; const float* b1 = (const float*)d_in[13];
    const float* W2 = (const float*)d_in[14]; const float* b2 = (const float*)d_in[15];
    const float* g1 = (const float*)d_in[16]; const float* beta1 = (const float*)d_in[17];
    const float* g2 = (const float*)d_in[18]; const float* beta2 = (const float*)d_in[19];
    const float* alpha = (const float*)d_in[20];

    const int N = in_sizes[0] / 128;
    const int E = in_sizes[2] / 2;

    char* w = (char*)d_ws;
    auto alloc = [&](size_t bytes) {
        char* p = w;
        w += (bytes + 255) & ~(size_t)255;
        return p;
    };
    bf16*  h      = (bf16*)alloc((size_t)N * 128 * 2);
    bf16*  QKVS   = (bf16*)alloc((size_t)N * 512 * 2);
    bf16*  Ep     = (bf16*)alloc((size_t)E * 128 * 2);
    float* xn     = (float*)alloc((size_t)N * 128 * 4);
    bf16*  h2     = (bf16*)alloc((size_t)N * 128 * 2);
    bf16*  t      = (bf16*)alloc((size_t)N * 512 * 2);
    int*   cnt    = (int*)alloc((size_t)N * 4);
    int*   cursor = (int*)alloc((size_t)N * 4);
    int*   offset = (int*)alloc((size_t)(N + 1) * 4);
    int*   srcs   = (int*)alloc((size_t)E * 4);
    int*   epos   = (int*)alloc((size_t)E * 4);
    bf16*  WTqkvs = (bf16*)alloc((size_t)512 * 128 * 2);
    bf16*  WTe    = (bf16*)alloc((size_t)128 * 128 * 2);
    bf16*  WT1    = (bf16*)alloc((size_t)512 * 128 * 2);
    bf16*  WT2    = (bf16*)alloc((size_t)128 * 512 * 2);
    float* bqkvs  = (float*)alloc((size_t)512 * 4);

    // weight prep (tiny)
    t_k<<<64, 256, 0, stream>>>(Wq, WTqkvs, 128, 128);
    t_k<<<64, 256, 0, stream>>>(Wk, WTqkvs + 128 * 128, 128, 128);
    t_k<<<64, 256, 0, stream>>>(Wv, WTqkvs + 256 * 128, 128, 128);
    t_k<<<64, 256, 0, stream>>>(Wskip, WTqkvs + 384 * 128, 128, 128);
    t_k<<<64, 256, 0, stream>>>(We, WTe, 128, 128);
    t_k<<<256, 256, 0, stream>>>(W1, WT1, 128, 512);
    t_k<<<256, 256, 0, stream>>>(W2, WT2, 512, 128);
    bcat_k<<<2, 256, 0, stream>>>(bq, bk, bv, bskip, bqkvs);

    // CSR build
    hipMemsetAsync(cnt, 0, (size_t)N * 4, stream);
    hipMemsetAsync(cursor, 0, (size_t)N * 4, stream);
    hist_k<<<(E + 255) / 256, 256, 0, stream>>>(ei, cnt, E);
    scan_k<<<1, 1024, 0, stream>>>(cnt, offset, N);
    scatter_k<<<(E + 255) / 256, 256, 0, stream>>>(ei, offset, cursor, srcs, epos, E);

    // LN1
    ln_k<<<(N + 3) / 4, 256, 0, stream>>>(x, g1, beta1, h, N);

    // fused Q|K|V|S GEMM -> QKVS [N][512]
    gemm2_k<0, false><<<dim3((N + 127) / 128, 4), 512, 0, stream>>>(h, WTqkvs, bqkvs, QKVS, nullptr, nullptr, N, 128, 512);

    // edge projection: Ep = edge_attr(f32) @ We -> bf16, rows scattered to dst-sorted order
    egemm_k<<<1280, 256, 0, stream>>>(edge_attr, WTe, Ep, epos, E);

    // fused gather: attention + normalize + skip + residual + LN2
    gather_k<<<(N + 3) / 4, 256, 0, stream>>>(srcs, offset, QKVS, Ep, x, alpha, g2, beta2, xn, h2, N);

    // FFN
    gemm2_k<2, false><<<dim3((N + 127) / 128, 4), 512, 0, stream>>>(h2, WT1, b1, t, nullptr, nullptr, N, 128, 512);
    gemm2_k<3, false><<<dim3((N + 127) / 128, 1), 512, 0, stream>>>(t, WT2, b2, d_out, xn, nullptr, N, 512, 128);
}

// Round 4
// 824.215 us; speedup vs baseline: 1.1456x; 1.0962x over previous
//
#include <hip/hip_runtime.h>
#include <hip/hip_bf16.h>

typedef __bf16 bf16x8 __attribute__((ext_vector_type(8)));
typedef __bf16 bf16x4 __attribute__((ext_vector_type(4)));
typedef __bf16 bf16x2 __attribute__((ext_vector_type(2)));
typedef float f32x4 __attribute__((ext_vector_type(4)));
using bf16 = __hip_bfloat16;

// ---------------------------------------------------------------------------
// Weight prep: WT[n*K + k] = (bf16) W[k*N + n]   (transpose + f32->bf16)
// ---------------------------------------------------------------------------
__global__ __launch_bounds__(256) void t_k(const float* __restrict__ W,
                                           bf16* __restrict__ WT, int K, int N)
{
    int idx = blockIdx.x * 256 + threadIdx.x;
    if (idx >= K * N) return;
    int n = idx / K, k = idx % K;
    WT[idx] = __float2bfloat16(W[(size_t)k * N + n]);
}

__global__ __launch_bounds__(256) void bcat_k(const float* __restrict__ a, const float* __restrict__ b,
                                              const float* __restrict__ c, const float* __restrict__ d,
                                              float* __restrict__ o)
{
    int i = threadIdx.x + blockIdx.x * 256;
    if (i >= 512) return;
    o[i] = (i < 128) ? a[i] : (i < 256) ? b[i - 128] : (i < 384) ? c[i - 256] : d[i - 384];
}

// ---------------------------------------------------------------------------
// MFMA GEMM (general, LDS-staged): used only for FFN2 (K=512).
// MODE 3: +resid -> f32 out.
// ---------------------------------------------------------------------------
template <int MODE, bool AF32>
__global__ __launch_bounds__(512) void gemm2_k(
    const void* __restrict__ Av, const bf16* __restrict__ WT,
    const float* __restrict__ bias, void* __restrict__ Cout,
    const float* __restrict__ resid, const int* __restrict__ rowperm,
    int M, int K, int Nout)
{
    __shared__ __bf16 As[128 * 128];
    __shared__ __bf16 Ws[128 * 128];

    const int tid  = threadIdx.x;
    const int wave = tid >> 6;
    const int lane = tid & 63;
    const int row0 = blockIdx.x * 128;
    const int col0 = blockIdx.y * 128;

    f32x4 acc[8];
#pragma unroll
    for (int i = 0; i < 8; i++) acc[i] = (f32x4){0.f, 0.f, 0.f, 0.f};

    for (int k0 = 0; k0 < K; k0 += 128) {
        // ---- stage A tile (128 x 128) ----
        if constexpr (AF32) {
            const float* A = (const float*)Av;
#pragma unroll
            for (int i = 0; i < 8; i++) {              // 4096 f32x4 chunks (8B bf16 out)
                int idx = tid + i * 512;
                int r = idx >> 5, c4 = idx & 31;
                bf16x4 o;
                if (row0 + r < M) {
                    f32x4 v = *reinterpret_cast<const f32x4*>(A + (size_t)(row0 + r) * K + k0 + c4 * 4);
#pragma unroll
                    for (int j = 0; j < 4; j++) o[j] = (__bf16)v[j];
                } else {
#pragma unroll
                    for (int j = 0; j < 4; j++) o[j] = (__bf16)0.f;
                }
                int col = (c4 >> 1) ^ (r & 7);
                *reinterpret_cast<bf16x4*>(&As[r * 128 + col * 8 + (c4 & 1) * 4]) = o;
            }
        } else {
            const bf16* A = (const bf16*)Av;
#pragma unroll
            for (int i = 0; i < 4; i++) {              // 2048 bf16x8 chunks
                int idx = tid + i * 512;
                int r = idx >> 4, c = idx & 15;
                bf16x8 v;
                if (row0 + r < M) {
                    v = *reinterpret_cast<const bf16x8*>(A + (size_t)(row0 + r) * K + k0 + c * 8);
                } else {
#pragma unroll
                    for (int j = 0; j < 8; j++) v[j] = (__bf16)0.f;
                }
                *reinterpret_cast<bf16x8*>(&As[r * 128 + ((c ^ (r & 7)) * 8)]) = v;
            }
        }
        // ---- stage W tile: WT rows col0..col0+127, k slice ----
#pragma unroll
        for (int i = 0; i < 4; i++) {
            int idx = tid + i * 512;
            int r = idx >> 4, c = idx & 15;
            bf16x8 v = *reinterpret_cast<const bf16x8*>(WT + (size_t)(col0 + r) * K + k0 + c * 8);
            *reinterpret_cast<bf16x8*>(&Ws[r * 128 + ((c ^ (r & 7)) * 8)]) = v;
        }
        __syncthreads();

        const int mrow = wave * 16 + (lane & 15);
        const int kq = lane >> 4;                       // 0..3
#pragma unroll
        for (int kk = 0; kk < 4; kk++) {                // K-steps of 32
            int cidx = kk * 4 + kq;                     // 16B chunk index (pre-swizzle)
            bf16x8 a = *reinterpret_cast<const bf16x8*>(&As[mrow * 128 + ((cidx ^ (mrow & 7)) * 8)]);
#pragma unroll
            for (int ct = 0; ct < 8; ct++) {
                int nrow = ct * 16 + (lane & 15);
                bf16x8 b = *reinterpret_cast<const bf16x8*>(&Ws[nrow * 128 + ((cidx ^ (nrow & 7)) * 8)]);
                acc[ct] = __builtin_amdgcn_mfma_f32_16x16x32_bf16(a, b, acc[ct], 0, 0, 0);
            }
        }
        __syncthreads();
    }

    // epilogue: C/D layout col=lane&15, row=(lane>>4)*4+reg
    const int rbase = row0 + wave * 16 + ((lane >> 4) << 2);
    int orow[4];
#pragma unroll
    for (int r = 0; r < 4; r++) {
        int row = rbase + r;
        orow[r] = (row < M) ? (rowperm ? rowperm[row] : row) : -1;
    }
#pragma unroll
    for (int ct = 0; ct < 8; ct++) {
        int col = col0 + ct * 16 + (lane & 15);
        float bv = bias ? bias[col] : 0.f;
#pragma unroll
        for (int r = 0; r < 4; r++) {
            if (orow[r] < 0) continue;
            float v = acc[ct][r] + bv;
            if constexpr (MODE == 2) v = v / (1.f + __expf(-v));
            if constexpr (MODE == 3) v += resid[(size_t)orow[r] * 128 + col];
            if constexpr (MODE == 3) {
                ((float*)Cout)[(size_t)orow[r] * Nout + col] = v;
            } else {
                ((bf16*)Cout)[(size_t)orow[r] * Nout + col] = __float2bfloat16(v);
            }
        }
    }
}

// ---------------------------------------------------------------------------
// Edge-projection GEMM, specialized: M huge, K=128, N=128, A in f32.
// W (128x128 bf16 = 32 KB) in swizzled LDS once; barrier-free grid-stride,
// one 16-row tile per wave, A global->reg in MFMA fragment layout.
// Output rows scattered via rowperm (dst-sorted Ep order).
// ---------------------------------------------------------------------------
__global__ __launch_bounds__(256) void egemm_k(
    const float* __restrict__ A, const bf16* __restrict__ WT,
    bf16* __restrict__ C, const int* __restrict__ rowperm, int M)
{
    __shared__ __bf16 Ws[128 * 128];
#pragma unroll
    for (int i = 0; i < 8; i++) {
        int idx = threadIdx.x + i * 256;
        int r = idx >> 4, c = idx & 15;
        bf16x8 v = *reinterpret_cast<const bf16x8*>(WT + r * 128 + c * 8);
        *reinterpret_cast<bf16x8*>(&Ws[r * 128 + ((c ^ (r & 7)) * 8)]) = v;
    }
    __syncthreads();

    const int lane = threadIdx.x & 63;
    const int wave = threadIdx.x >> 6;
    const int r16  = lane & 15;
    const int kq   = lane >> 4;                         // 0..3
    const int ntiles = (M + 15) >> 4;

    for (int t = blockIdx.x * 4 + wave; t < ntiles; t += gridDim.x * 4) {
        const int row0 = t * 16;
        const int arow = row0 + r16;

        bf16x8 a[4];
        if (arow < M) {
            const float* ap = A + (size_t)arow * 128 + kq * 8;
#pragma unroll
            for (int kk = 0; kk < 4; kk++) {
                f32x4 lo = *reinterpret_cast<const f32x4*>(ap + kk * 32);
                f32x4 hi = *reinterpret_cast<const f32x4*>(ap + kk * 32 + 4);
#pragma unroll
                for (int j = 0; j < 4; j++) {
                    a[kk][j]     = (__bf16)lo[j];
                    a[kk][j + 4] = (__bf16)hi[j];
                }
            }
        } else {
#pragma unroll
            for (int kk = 0; kk < 4; kk++)
#pragma unroll
                for (int j = 0; j < 8; j++) a[kk][j] = (__bf16)0.f;
        }

        f32x4 acc[8];
#pragma unroll
        for (int i = 0; i < 8; i++) acc[i] = (f32x4){0.f, 0.f, 0.f, 0.f};
#pragma unroll
        for (int kk = 0; kk < 4; kk++) {
            int cidx = kk * 4 + kq;
#pragma unroll
            for (int ct = 0; ct < 8; ct++) {
                int nrow = ct * 16 + r16;
                bf16x8 b = *reinterpret_cast<const bf16x8*>(&Ws[nrow * 128 + ((cidx ^ (nrow & 7)) * 8)]);
                acc[ct] = __builtin_amdgcn_mfma_f32_16x16x32_bf16(a[kk], b, acc[ct], 0, 0, 0);
            }
        }

        const int rbase = row0 + (kq << 2);
#pragma unroll
        for (int r = 0; r < 4; r++) {
            int row = rbase + r;
            if (row >= M) continue;
            size_t orow = (size_t)(rowperm ? rowperm[row] : row);
#pragma unroll
            for (int ct = 0; ct < 8; ct++) {
                C[orow * 128 + ct * 16 + r16] = __float2bfloat16(acc[ct][r]);
            }
        }
    }
}

// ---------------------------------------------------------------------------
// Node GEMM, specialized: M huge, K=128, A bf16, Nout split by blockIdx.y*128.
// Same barrier-free structure as egemm_k. MODE 0: bias, MODE 2: bias+silu.
// ---------------------------------------------------------------------------
template <int MODE>
__global__ __launch_bounds__(256) void ngemm_k(
    const bf16* __restrict__ A, const bf16* __restrict__ WT,
    const float* __restrict__ bias, bf16* __restrict__ C,
    int M, int Nout)
{
    __shared__ __bf16 Ws[128 * 128];
    const int col0 = blockIdx.y * 128;
#pragma unroll
    for (int i = 0; i < 8; i++) {
        int idx = threadIdx.x + i * 256;
        int r = idx >> 4, c = idx & 15;
        bf16x8 v = *reinterpret_cast<const bf16x8*>(WT + (size_t)(col0 + r) * 128 + c * 8);
        *reinterpret_cast<bf16x8*>(&Ws[r * 128 + ((c ^ (r & 7)) * 8)]) = v;
    }
    __syncthreads();

    const int lane = threadIdx.x & 63;
    const int wave = threadIdx.x >> 6;
    const int r16  = lane & 15;
    const int kq   = lane >> 4;                         // 0..3
    const int ntiles = (M + 15) >> 4;

    float bcol[8];
#pragma unroll
    for (int ct = 0; ct < 8; ct++) bcol[ct] = bias[col0 + ct * 16 + r16];

    for (int t = blockIdx.x * 4 + wave; t < ntiles; t += gridDim.x * 4) {
        const int row0 = t * 16;
        const int arow = row0 + r16;

        bf16x8 a[4];
        if (arow < M) {
            const bf16* ap = A + (size_t)arow * 128 + kq * 8;
#pragma unroll
            for (int kk = 0; kk < 4; kk++)
                a[kk] = *reinterpret_cast<const bf16x8*>(ap + kk * 32);
        } else {
#pragma unroll
            for (int kk = 0; kk < 4; kk++)
#pragma unroll
                for (int j = 0; j < 8; j++) a[kk][j] = (__bf16)0.f;
        }

        f32x4 acc[8];
#pragma unroll
        for (int i = 0; i < 8; i++) acc[i] = (f32x4){0.f, 0.f, 0.f, 0.f};
#pragma unroll
        for (int kk = 0; kk < 4; kk++) {
            int cidx = kk * 4 + kq;
#pragma unroll
            for (int ct = 0; ct < 8; ct++) {
                int nrow = ct * 16 + r16;
                bf16x8 b = *reinterpret_cast<const bf16x8*>(&Ws[nrow * 128 + ((cidx ^ (nrow & 7)) * 8)]);
                acc[ct] = __builtin_amdgcn_mfma_f32_16x16x32_bf16(a[kk], b, acc[ct], 0, 0, 0);
            }
        }

        const int rbase = row0 + (kq << 2);
#pragma unroll
        for (int r = 0; r < 4; r++) {
            int row = rbase + r;
            if (row >= M) continue;
#pragma unroll
            for (int ct = 0; ct < 8; ct++) {
                float v = acc[ct][r] + bcol[ct];
                if constexpr (MODE == 2) v = v / (1.f + __expf(-v));
                C[(size_t)row * Nout + col0 + ct * 16 + r16] = __float2bfloat16(v);
            }
        }
    }
}

// ---------------------------------------------------------------------------
// LayerNorm: one wave per row (D=128, 2 channels/lane). f32 in -> bf16 out.
// ---------------------------------------------------------------------------
__global__ __launch_bounds__(256) void ln_k(
    const float* __restrict__ x, const float* __restrict__ g,
    const float* __restrict__ beta, bf16* __restrict__ h, int Nrows)
{
    int row = blockIdx.x * 4 + (threadIdx.x >> 6);
    int lane = threadIdx.x & 63;
    if (row >= Nrows) return;
    size_t base = (size_t)row * 128;
    float v0 = x[base + lane], v1 = x[base + lane + 64];
    float s = v0 + v1, ss = v0 * v0 + v1 * v1;
#pragma unroll
    for (int off = 32; off; off >>= 1) {
        s += __shfl_xor(s, off, 64);
        ss += __shfl_xor(ss, off, 64);
    }
    float mu = s * (1.f / 128.f);
    float var = ss * (1.f / 128.f) - mu * mu;
    float rs = rsqrtf(var + 1e-5f);
    h[base + lane]      = __float2bfloat16((v0 - mu) * rs * g[lane] + beta[lane]);
    h[base + lane + 64] = __float2bfloat16((v1 - mu) * rs * g[lane + 64] + beta[lane + 64]);
}

// ---------------------------------------------------------------------------
// CSR build
// ---------------------------------------------------------------------------
__global__ __launch_bounds__(256) void hist_k(const int* __restrict__ ei, int* __restrict__ cnt, int E)
{
    int e = blockIdx.x * 256 + threadIdx.x;
    if (e < E) atomicAdd(&cnt[ei[E + e]], 1);
}

// Single-block scan, shuffle-based: wave-inclusive scan (no barriers) +
// serial combine of 16 wave sums. 4 barriers/chunk vs 22 in the old version.
__global__ __launch_bounds__(1024) void scan_k(const int* __restrict__ cnt, int* __restrict__ offset, int N)
{
    __shared__ int wsum[16];
    __shared__ int s_running;
    int tid  = threadIdx.x;
    int lane = tid & 63;
    int wv   = tid >> 6;
    if (tid == 0) { s_running = 0; offset[0] = 0; }
    __syncthreads();
    for (int base = 0; base < N; base += 1024) {
        int v = (base + tid < N) ? cnt[base + tid] : 0;
        int s = v;
#pragma unroll
        for (int d = 1; d < 64; d <<= 1) {
            int t = __shfl_up(s, d, 64);
            if (lane >= d) s += t;
        }
        if (lane == 63) wsum[wv] = s;
        __syncthreads();
        if (tid == 0) {
            int acc = 0;
#pragma unroll
            for (int i = 0; i < 16; i++) { acc += wsum[i]; wsum[i] = acc; }
        }
        __syncthreads();
        int run = s_running;
        int wexcl = (wv > 0) ? wsum[wv - 1] : 0;
        if (base + tid < N) offset[base + tid + 1] = run + wexcl + s;
        __syncthreads();
        if (tid == 0) s_running = run + wsum[15];
        __syncthreads();
    }
}

// scatter: srcs[j] = src for slot j (dst-sorted); epos[e] = j so the edge
// projection GEMM can write Ep rows directly in dst-sorted order.
__global__ __launch_bounds__(256) void scatter_k(
    const int* __restrict__ ei, const int* __restrict__ offset,
    int* __restrict__ cursor, int* __restrict__ srcs, int* __restrict__ epos, int E)
{
    int e = blockIdx.x * 256 + threadIdx.x;
    if (e >= E) return;
    int src = ei[e];
    int dst = ei[E + e];
    int r = atomicAdd(&cursor[dst], 1);
    int j = offset[dst] + r;
    srcs[j] = src;
    epos[e] = j;
}

// ---------------------------------------------------------------------------
// Fused gather: one wave per dst node; QKVS layout [N][512] = Q|K|V|S (bf16).
// Ep is stored in dst-sorted order -> sequential streaming reads.
// p = exp(q.(k+e)/4); register accumulation; then norm+skip+resid+LN2.
// ---------------------------------------------------------------------------
__global__ __launch_bounds__(256) void gather_k(
    const int* __restrict__ srcs, const int* __restrict__ offset,
    const bf16* __restrict__ QKVS, const bf16* __restrict__ Ep,
    const float* __restrict__ x, const float* __restrict__ alpha,
    const float* __restrict__ g, const float* __restrict__ beta,
    float* __restrict__ xn, bf16* __restrict__ h2, int N)
{
    int node = blockIdx.x * 4 + (threadIdx.x >> 6);
    if (node >= N) return;
    int lane = threadIdx.x & 63;
    int c = lane * 2;

    bf16x2 qv = *reinterpret_cast<const bf16x2*>(QKVS + (size_t)node * 512 + c);
    float q0 = (float)qv[0], q1 = (float)qv[1];

    int start = offset[node], end = offset[node + 1];
    float den = 0.f, num0 = 0.f, num1 = 0.f;

    bf16x2 kv, vv, ev;
    if (start < end) {
        const bf16* sp = QKVS + (size_t)srcs[start] * 512 + c;
        kv = *reinterpret_cast<const bf16x2*>(sp + 128);
        vv = *reinterpret_cast<const bf16x2*>(sp + 256);
        ev = *reinterpret_cast<const bf16x2*>(Ep + (size_t)start * 128 + c);
    }
    for (int j = start; j < end; j++) {
        bf16x2 kc = kv, vc = vv, ec = ev;
        if (j + 1 < end) {
            const bf16* sp = QKVS + (size_t)srcs[j + 1] * 512 + c;
            kv = *reinterpret_cast<const bf16x2*>(sp + 128);
            vv = *reinterpret_cast<const bf16x2*>(sp + 256);
            ev = *reinterpret_cast<const bf16x2*>(Ep + (size_t)(j + 1) * 128 + c);
        }
        float e0 = (float)ec[0], e1 = (float)ec[1];
        float part = q0 * ((float)kc[0] + e0) + q1 * ((float)kc[1] + e1);
        part += __shfl_xor(part, 1, 64);
        part += __shfl_xor(part, 2, 64);
        part += __shfl_xor(part, 4, 64);
        float p = __expf(part * 0.25f);
        den  += p;
        num0 += p * ((float)vc[0] + e0);
        num1 += p * ((float)vc[1] + e1);
    }

    size_t base = (size_t)node * 128;
    float invz = 1.f / (den + 1e-16f);
    float al = alpha[0];
    float s0 = (float)QKVS[(size_t)node * 512 + 384 + c];
    float s1 = (float)QKVS[(size_t)node * 512 + 384 + c + 1];
    float o0 = num0 * invz + s0;
    float o1 = num1 * invz + s1;
    float x0 = x[base + c] + al * o0;
    float x1 = x[base + c + 1] + al * o1;
    xn[base + c] = x0;
    xn[base + c + 1] = x1;

    float s = x0 + x1, ss = x0 * x0 + x1 * x1;
#pragma unroll
    for (int off = 32; off; off >>= 1) {
        s += __shfl_xor(s, off, 64);
        ss += __shfl_xor(ss, off, 64);
    }
    float mu = s * (1.f / 128.f);
    float var = ss * (1.f / 128.f) - mu * mu;
    float rs = rsqrtf(var + 1e-5f);
    h2[base + c]     = __float2bfloat16((x0 - mu) * rs * g[c] + beta[c]);
    h2[base + c + 1] = __float2bfloat16((x1 - mu) * rs * g[c + 1] + beta[c + 1]);
}

// ---------------------------------------------------------------------------
extern "C" void kernel_launch(void* const* d_in, const int* in_sizes, int n_in,
                              void* d_out, int out_size, void* d_ws, size_t ws_size,
                              hipStream_t stream)
{
    const float* x         = (const float*)d_in[0];
    const float* edge_attr = (const float*)d_in[1];
    const int*   ei        = (const int*)d_in[2];
    const float* Wq = (const float*)d_in[3];  const float* bq = (const float*)d_in[4];
    const float* Wk = (const float*)d_in[5];  const float* bk = (const float*)d_in[6];
    const float* Wv = (const float*)d_in[7];  const float* bv = (const float*)d_in[8];
    const float* We = (const float*)d_in[9];
    const float* Wskip = (const float*)d_in[10]; const float* bskip = (const float*)d_in[11];
    const float* W1 = (const float*)d_in[12]; const float* b1 = (const float*)d_in[13];
    const float* W2 = (const float*)d_in[14]; const float* b2 = (const float*)d_in[15];
    const float* g1 = (const float*)d_in[16]; const float* beta1 = (const float*)d_in[17];
    const float* g2 = (const float*)d_in[18]; const float* beta2 = (const float*)d_in[19];
    const float* alpha = (const float*)d_in[20];

    const int N = in_sizes[0] / 128;
    const int E = in_sizes[2] / 2;

    char* w = (char*)d_ws;
    auto alloc = [&](size_t bytes) {
        char* p = w;
        w += (bytes + 255) & ~(size_t)255;
        return p;
    };
    bf16*  h      = (bf16*)alloc((size_t)N * 128 * 2);
    bf16*  QKVS   = (bf16*)alloc((size_t)N * 512 * 2);
    bf16*  Ep     = (bf16*)alloc((size_t)E * 128 * 2);
    float* xn     = (float*)alloc((size_t)N * 128 * 4);
    bf16*  h2     = (bf16*)alloc((size_t)N * 128 * 2);
    bf16*  t      = (bf16*)alloc((size_t)N * 512 * 2);
    int*   cnt    = (int*)alloc((size_t)N * 4);
    int*   cursor = (int*)alloc((size_t)N * 4);
    int*   offset = (int*)alloc((size_t)(N + 1) * 4);
    int*   srcs   = (int*)alloc((size_t)E * 4);
    int*   epos   = (int*)alloc((size_t)E * 4);
    bf16*  WTqkvs = (bf16*)alloc((size_t)512 * 128 * 2);
    bf16*  WTe    = (bf16*)alloc((size_t)128 * 128 * 2);
    bf16*  WT1    = (bf16*)alloc((size_t)512 * 128 * 2);
    bf16*  WT2    = (bf16*)alloc((size_t)128 * 512 * 2);
    float* bqkvs  = (float*)alloc((size_t)512 * 4);

    // weight prep (tiny)
    t_k<<<64, 256, 0, stream>>>(Wq, WTqkvs, 128, 128);
    t_k<<<64, 256, 0, stream>>>(Wk, WTqkvs + 128 * 128, 128, 128);
    t_k<<<64, 256, 0, stream>>>(Wv, WTqkvs + 256 * 128, 128, 128);
    t_k<<<64, 256, 0, stream>>>(Wskip, WTqkvs + 384 * 128, 128, 128);
    t_k<<<64, 256, 0, stream>>>(We, WTe, 128, 128);
    t_k<<<256, 256, 0, stream>>>(W1, WT1, 128, 512);
    t_k<<<256, 256, 0, stream>>>(W2, WT2, 512, 128);
    bcat_k<<<2, 256, 0, stream>>>(bq, bk, bv, bskip, bqkvs);

    // CSR build
    hipMemsetAsync(cnt, 0, (size_t)N * 4, stream);
    hipMemsetAsync(cursor, 0, (size_t)N * 4, stream);
    hist_k<<<(E + 255) / 256, 256, 0, stream>>>(ei, cnt, E);
    scan_k<<<1, 1024, 0, stream>>>(cnt, offset, N);
    scatter_k<<<(E + 255) / 256, 256, 0, stream>>>(ei, offset, cursor, srcs, epos, E);

    // LN1
    ln_k<<<(N + 3) / 4, 256, 0, stream>>>(x, g1, beta1, h, N);

    // fused Q|K|V|S GEMM -> QKVS [N][512]
    ngemm_k<0><<<dim3(256, 4), 256, 0, stream>>>(h, WTqkvs, bqkvs, QKVS, N, 512);

    // edge projection: Ep = edge_attr(f32) @ We -> bf16, rows scattered to dst-sorted order
    egemm_k<<<1280, 256, 0, stream>>>(edge_attr, WTe, Ep, epos, E);

    // fused gather: attention + normalize + skip + residual + LN2
    gather_k<<<(N + 3) / 4, 256, 0, stream>>>(srcs, offset, QKVS, Ep, x, alpha, g2, beta2, xn, h2, N);

    // FFN
    ngemm_k<2><<<dim3(256, 4), 256, 0, stream>>>(h2, WT1, b1, t, N, 512);
    gemm2_k<3, false><<<dim3((N + 127) / 128, 1), 512, 0, stream>>>(t, WT2, b2, d_out, xn, nullptr, N, 512, 128);
}